// Round 14
// baseline (341.647 us; speedup 1.0000x reference)
//
#include <hip/hip_runtime.h>
#include <hip/hip_bf16.h>
#include <math.h>

namespace {

constexpr int Kn   = 32;
constexpr int CIN  = 64;
constexpr int COUT = 64;
constexpr int Mn   = 8;
constexpr int HIDn = 16;
constexpr int NK   = 65536;         // N*K
constexpr int PTOT = 262144;        // B*N*K
constexpr float EPSf = 1e-5f;

constexpr int NBLK = 1024;          // 4 blocks/CU, all resident
constexpr int NTHR = 256;           // 4 waves (256-thr blocks -> 128-reg budget)
constexpr int NREP = 8;             // stat/barrier replica banks

// ws layout (floats): replica r at [r*256, r*256+256):
//   [+0,16) bn1 sum, [+16,32) bn1 sumsq, [+64,128) bn2 sum, [+128,192) bn2 sq
// barrier: 8 ints at float-offset 2048 + i*16 (64 B apart)
// bf16 Wb fragments (written by k_prep): float-offset 4096, 65536 bytes
constexpr int WS_ZERO = 4096;

typedef short bf16x8  __attribute__((ext_vector_type(8)));
typedef float f32x4   __attribute__((ext_vector_type(4)));
typedef float f32x16  __attribute__((ext_vector_type(16)));

__device__ __forceinline__ short f2bf(float f) {
  union { __hip_bfloat16 h; unsigned short u; } cv;
  cv.h = __float2bfloat16(f);
  return (short)cv.u;
}

__device__ __forceinline__ float ws_ld(const float* p) {
  return __hip_atomic_load(p, __ATOMIC_RELAXED, __HIP_MEMORY_SCOPE_AGENT);
}

// Manual grid barrier, 8-way-split monotone counters (round-9-validated).
// __syncthreads() drains vmcnt(0) before the arrive-increment.
__device__ __forceinline__ void gridbar(float* ws, int blk, int tid,
                                        int target) {
  int* cnt = (int*)(ws + 2048);
  __syncthreads();
  if (tid == 0) {
    __hip_atomic_fetch_add(&cnt[(blk & (NREP - 1)) * 16], 1, __ATOMIC_ACQ_REL,
                           __HIP_MEMORY_SCOPE_AGENT);
    int s;
    do {
      s = 0;
#pragma unroll
      for (int i = 0; i < NREP; ++i)
        s += __hip_atomic_load(&cnt[i * 16], __ATOMIC_ACQUIRE,
                               __HIP_MEMORY_SCOPE_AGENT);
      if (s < target) __builtin_amdgcn_s_sleep(8);
    } while (s < target);
  }
  __syncthreads();
}

// Build 14-ch geometric feature and h = w1 @ x (16 channels) for one position.
__device__ __forceinline__ void geom_h(
    const float* __restrict__ xyz, const float* __restrict__ dist,
    const float* __restrict__ nrm, const float* __restrict__ ang,
    const float* __restrict__ w1, int b, int rem, float h[HIDn]) {
  const int cbase = rem & ~(Kn - 1);   // k = 0 element of this (b, n)
  float x[14];
  const float invd = 1.0f / (1.0f + dist[b * NK + rem]);
  float xe = 0.f, ne = 0.f;
#pragma unroll
  for (int d = 0; d < 3; ++d) {
    const int base = (b * 3 + d) * NK;
    const float gx = xyz[base + rem];
    const float gn = nrm[base + rem];
    const float cn = nrm[base + cbase];
    const float ga = ang[base + rem];
    const float nd = gn - cn;
    x[d] = gx; x[4 + d] = gn; x[7 + d] = nd; x[11 + d] = ga;
    xe += gx * gx; ne += nd * nd;
  }
  x[3]  = sqrtf(xe);
  x[10] = sqrtf(ne);
#pragma unroll
  for (int i = 0; i < 14; ++i) x[i] *= invd;
#pragma unroll
  for (int o = 0; o < HIDn; ++o) {
    float s = 0.f;
#pragma unroll
    for (int c = 0; c < 14; ++c) s = fmaf(w1[o * 14 + c], x[c], s);
    h[o] = s;
  }
}

__global__ __launch_bounds__(512) void k0_zero(float* __restrict__ ws) {
  for (int i = threadIdx.x; i < WS_ZERO; i += 512) ws[i] = 0.f;
}

// Pre-convert Wb -> fragment-major bf16 in ws (deterministic every launch).
// Element: wf[(fi*64+l)*8+j] = bf16(wb[c*512 + j*64 + o]),
// fi=kk*2+ct, c=kk*2+(l>>5), o=ct*32+(l&31)  (round-8-validated labeling).
__global__ __launch_bounds__(256) void k_prep(const float* __restrict__ wb,
                                              float* __restrict__ ws) {
  const int t  = blockIdx.x * 256 + threadIdx.x;   // 0..4095
  const int fi = t >> 6, l = t & 63;
  const int kk = fi >> 1, ct = fi & 1;
  const int c  = kk * 2 + (l >> 5);
  const int o  = ct * 32 + (l & 31);
  bf16x8 frag;
#pragma unroll
  for (int j = 0; j < 8; ++j) frag[j] = f2bf(wb[c * 512 + j * 64 + o]);
  *reinterpret_cast<bf16x8*>(reinterpret_cast<short*>(ws + 4096) + t * 8) = frag;
}

// Persistent kernel, round-14 restructure: 256-thread blocks (4 waves) break
// the 64-VGPR straitjacket of 1024-thread workgroups (rounds 4-11) -> both
// position-groups' accumulators stay in registers (64 VGPR, no LDS park,
// exact f32). B-fragments come from the k_prep bf16 buffer via coalesced
// global loads (same 64 KB for all waves -> L2-hot); each B-load feeds both
// groups (4 MFMA / 2 B-reads). 1024 blocks, 4/CU, all resident.
__global__ __launch_bounds__(NTHR, 4) void kmain(
    const float* __restrict__ xyz, const float* __restrict__ dist,
    const float* __restrict__ nrm, const float* __restrict__ ang,
    const float* __restrict__ feature, const float* __restrict__ w1,
    const float* __restrict__ g1, const float* __restrict__ b1,
    const float* __restrict__ w2, const float* __restrict__ bias2,
    const float* __restrict__ gamma, const float* __restrict__ beta,
    float* __restrict__ ws, float* __restrict__ out) {
  __shared__ float red[4][128];              // 2 KB reductions
  __shared__ float bnp[160];  // [0:16] sc1 [16:32] sh1 [32:96] sc2 [96:160] sh2

  const int tid = threadIdx.x;
  const int l   = tid & 63;
  const int w   = tid >> 6;          // wave 0..3
  const int lg  = l >> 5;            // lane half 0..1 (k-group for 32x32x16)
  const int col = l & 31;            // A row (position) / B-D col (output)

  const int blk = blockIdx.x;
  const int rep = (blk & (NREP - 1)) * 256;   // stat replica bank
  const int pos = blk * NTHR + tid;  // this thread's position (phases A & C)
  const int b   = pos >> 16;         // uniform per block (256 | NK)
  const int rem = pos & (NK - 1);

  // ---- phase A: geom + h (kept in regs), BN1 sums ----
  float h[HIDn];
  geom_h(xyz, dist, nrm, ang, w1, b, rem, h);
  {
    float v[32];
#pragma unroll
    for (int i = 0; i < 16; ++i) { v[i] = h[i]; v[16 + i] = h[i] * h[i]; }
#pragma unroll
    for (int off = 32; off >= 1; off >>= 1) {
#pragma unroll
      for (int i = 0; i < 32; ++i) v[i] += __shfl_xor(v[i], off);
    }
    float mv = 0.f;
#pragma unroll
    for (int i = 0; i < 32; ++i) { if (l == i) mv = v[i]; }
    if (l < 32) red[w][l] = mv;
    __syncthreads();
    if (tid < 32) {
      const float tot = red[0][tid] + red[1][tid] + red[2][tid] + red[3][tid];
      atomicAdd(&ws[rep + tid], tot);   // replica: [0:16)=sum, [16:32)=sumsq
    }
  }

  gridbar(ws, blk, tid, NBLK);   // ---- grid barrier #1 ----

  // ---- phase B: finalize BN1 (sum the 8 replicas) ----
  if (tid < HIDn) {
    float sm = 0.f, sq = 0.f;
#pragma unroll
    for (int r = 0; r < NREP; ++r) {
      sm += ws_ld(&ws[r * 256 + tid]);
      sq += ws_ld(&ws[r * 256 + 16 + tid]);
    }
    const float inv  = 1.0f / (float)PTOT;
    const float mean = sm * inv;
    const float var  = sq * inv - mean * mean;
    const float s    = g1[tid] * rsqrtf(var + EPSf);
    bnp[tid]      = s;
    bnp[16 + tid] = b1[tid] - mean * s;
  }
  __syncthreads();

  // ---- phase C: scorenet from cached h; pack scores to bf16 words ----
  unsigned scp[4];
  {
#pragma unroll
    for (int o = 0; o < HIDn; ++o)
      h[o] = fmaxf(fmaf(h[o], bnp[o], bnp[16 + o]), 0.f);
    float s[Mn];
#pragma unroll
    for (int m = 0; m < Mn; ++m) {
      float a = bias2[m];
#pragma unroll
      for (int j = 0; j < HIDn; ++j) a = fmaf(w2[m * HIDn + j], h[j], a);
      s[m] = a;
    }
    float mx = s[0];
#pragma unroll
    for (int m = 1; m < Mn; ++m) mx = fmaxf(mx, s[m]);
    float sc[Mn];
    float ssum = 0.f;
#pragma unroll
    for (int m = 0; m < Mn; ++m) { sc[m] = expf(s[m] - mx); ssum += sc[m]; }
    const float inv = 1.0f / (ssum + expf(-mx));   // softmax_one
#pragma unroll
    for (int m = 0; m < Mn; ++m) sc[m] *= inv;
#pragma unroll
    for (int j = 0; j < 4; ++j) {
      scp[j] = (unsigned)(unsigned short)f2bf(sc[2 * j]) |
               ((unsigned)(unsigned short)f2bf(sc[2 * j + 1]) << 16);
    }
  }

  // ---- GEMM: wave owns 64 positions (2 groups of 32), all acc in regs ----
  const int wrem = (blk * NTHR + w * 64) & (NK - 1);
  const short* __restrict__ wf = reinterpret_cast<const short*>(ws + 4096);
  unsigned sg0[4], sg1[4];
#pragma unroll
  for (int j = 0; j < 4; ++j) {
    sg0[j] = __shfl(scp[j], col);        // group-0 rows: lanes 0..31
    sg1[j] = __shfl(scp[j], 32 + col);   // group-1 rows: lanes 32..63
  }
  f32x16 a00, a01, a10, a11;   // acc[group][ct]
#pragma unroll
  for (int i = 0; i < 16; ++i) { a00[i] = 0.f; a01[i] = 0.f;
                                 a10[i] = 0.f; a11[i] = 0.f; }
  const float* fp0 = feature + (size_t)b * CIN * NK + wrem +
                     (size_t)lg * NK + col;
  const float* fp1 = fp0 + 32;

#pragma unroll 4
  for (int kk = 0; kk < 32; ++kk) {
    const bf16x8 b0 =
        *reinterpret_cast<const bf16x8*>(&wf[((kk * 2 + 0) * 64 + l) * 8]);
    const bf16x8 b1 =
        *reinterpret_cast<const bf16x8*>(&wf[((kk * 2 + 1) * 64 + l) * 8]);
    const float fA0 = *fp0;
    const float fA1 = *fp1;
    fp0 += 2 * NK; fp1 += 2 * NK;
    bf16x8 av0, av1;
#pragma unroll
    for (int j = 0; j < 4; ++j) {
      const float s0lo = __uint_as_float(sg0[j] << 16);
      const float s0hi = __uint_as_float(sg0[j] & 0xffff0000u);
      const float s1lo = __uint_as_float(sg1[j] << 16);
      const float s1hi = __uint_as_float(sg1[j] & 0xffff0000u);
      av0[2 * j]     = f2bf(fA0 * s0lo);
      av0[2 * j + 1] = f2bf(fA0 * s0hi);
      av1[2 * j]     = f2bf(fA1 * s1lo);
      av1[2 * j + 1] = f2bf(fA1 * s1hi);
    }
    a00 = __builtin_amdgcn_mfma_f32_32x32x16_bf16(av0, b0, a00, 0, 0, 0);
    a01 = __builtin_amdgcn_mfma_f32_32x32x16_bf16(av0, b1, a01, 0, 0, 0);
    a10 = __builtin_amdgcn_mfma_f32_32x32x16_bf16(av1, b0, a10, 0, 0, 0);
    a11 = __builtin_amdgcn_mfma_f32_32x32x16_bf16(av1, b1, a11, 0, 0, 0);
  }

  // ---- BN2 partial sums (both groups combined per output channel) ----
  {
    float s0s = 0.f, q0s = 0.f, s1s = 0.f, q1s = 0.f;
#pragma unroll
    for (int i = 0; i < 16; ++i) {
      s0s += a00[i] + a10[i];
      q0s += a00[i] * a00[i] + a10[i] * a10[i];
      s1s += a01[i] + a11[i];
      q1s += a01[i] * a01[i] + a11[i] * a11[i];
    }
    s0s += __shfl_xor(s0s, 32); q0s += __shfl_xor(q0s, 32);
    s1s += __shfl_xor(s1s, 32); q1s += __shfl_xor(q1s, 32);
    if (l < 32) {
      red[w][col]      = s0s; red[w][32 + col] = s1s;
      red[w][64 + col] = q0s; red[w][96 + col] = q1s;
    }
    __syncthreads();
    if (tid < 128) {
      const float tot = red[0][tid] + red[1][tid] + red[2][tid] + red[3][tid];
      atomicAdd(&ws[rep + 64 + tid], tot);  // [64:128)=sum2, [128:192)=sq2
    }
  }

  gridbar(ws, blk, tid, 2 * NBLK);   // ---- grid barrier #2 ----

  // ---- phase D: finalize BN2 (sum the 8 replicas) ----
  if (tid < COUT) {
    float sm = 0.f, sq = 0.f;
#pragma unroll
    for (int r = 0; r < NREP; ++r) {
      sm += ws_ld(&ws[r * 256 + 64 + tid]);
      sq += ws_ld(&ws[r * 256 + 128 + tid]);
    }
    const float inv  = 1.0f / (float)PTOT;
    const float mean = sm * inv;
    const float var  = sq * inv - mean * mean;
    const float s    = gamma[tid] * rsqrtf(var + EPSf);
    bnp[32 + tid] = s;
    bnp[96 + tid] = beta[tid] - mean * s;
  }
  __syncthreads();

  // ---- phase E: BN2 + ReLU from registers (exact), single global write ----
  // D mapping (m74/m101): o = ct*32+col; reg r -> position (r&3)+8*(r>>2)+4*lg
  // -> reg-quad q = 4 consecutive positions at q*8 + 4*lg.
  float* obase = out + (size_t)b * COUT * NK + wrem;
#pragma unroll
  for (int ct = 0; ct < 2; ++ct) {
    const int o = ct * 32 + col;
    const float scl = bnp[32 + o];
    const float sh  = bnp[96 + o];
    float* orow = obase + (size_t)o * NK;
#pragma unroll
    for (int q = 0; q < 4; ++q) {
      f32x4 v0, v1;
#pragma unroll
      for (int i = 0; i < 4; ++i) {
        const float g0 = ct ? a01[q * 4 + i] : a00[q * 4 + i];
        const float g1 = ct ? a11[q * 4 + i] : a10[q * 4 + i];
        v0[i] = fmaxf(fmaf(g0, scl, sh), 0.f);
        v1[i] = fmaxf(fmaf(g1, scl, sh), 0.f);
      }
      *reinterpret_cast<f32x4*>(&orow[q * 8 + 4 * lg]) = v0;
      *reinterpret_cast<f32x4*>(&orow[32 + q * 8 + 4 * lg]) = v1;
    }
  }
}

}  // namespace

extern "C" void kernel_launch(void* const* d_in, const int* in_sizes, int n_in,
                              void* d_out, int out_size, void* d_ws, size_t ws_size,
                              hipStream_t stream) {
  const float* xyz     = (const float*)d_in[0];
  const float* dist    = (const float*)d_in[1];
  const float* nrm     = (const float*)d_in[2];
  const float* ang     = (const float*)d_in[3];
  const float* feature = (const float*)d_in[4];
  const float* w1      = (const float*)d_in[5];
  const float* g1      = (const float*)d_in[6];
  const float* b1      = (const float*)d_in[7];
  const float* w2      = (const float*)d_in[8];
  const float* bias2   = (const float*)d_in[9];
  const float* wb      = (const float*)d_in[10];
  const float* gamma   = (const float*)d_in[11];
  const float* beta    = (const float*)d_in[12];
  float* out = (float*)d_out;
  float* ws  = (float*)d_ws;

  hipLaunchKernelGGL(k0_zero, dim3(1), dim3(512), 0, stream, ws);
  hipLaunchKernelGGL(k_prep, dim3(16), dim3(256), 0, stream, wb, ws);
  hipLaunchKernelGGL(kmain, dim3(NBLK), dim3(NTHR), 0, stream,
                     xyz, dist, nrm, ang, feature, w1, g1, b1,
                     w2, bias2, gamma, beta, ws, out);
}

// Round 15
// 92.200 us; speedup vs baseline: 3.7055x; 3.7055x over previous
//
#include <hip/hip_runtime.h>
#include <hip/hip_bf16.h>
#include <math.h>

namespace {

constexpr int Kn   = 32;
constexpr int CIN  = 64;
constexpr int COUT = 64;
constexpr int Mn   = 8;
constexpr int HIDn = 16;
constexpr int NK   = 65536;         // N*K
constexpr int PTOT = 262144;        // B*N*K
constexpr float EPSf = 1e-5f;

constexpr int NBLK = 256;           // == #CUs: 1 block/CU, all resident
constexpr int NTHR = 1024;          // 16 waves

// ws float-offset layout
constexpr int WS_SUM1 = 0;    // 16 floats
constexpr int WS_SQ1  = 16;   // 16
constexpr int WS_SUM2 = 64;   // 64
constexpr int WS_SQ2  = 128;  // 64
constexpr int WS_BAR  = 192;  // int barrier counter (monotone)
constexpr int WS_TOT  = 256;

typedef short bf16x8  __attribute__((ext_vector_type(8)));
typedef float f32x4   __attribute__((ext_vector_type(4)));
typedef float f32x16  __attribute__((ext_vector_type(16)));

__device__ __forceinline__ short f2bf(float f) {
  union { __hip_bfloat16 h; unsigned short u; } cv;
  cv.h = __float2bfloat16(f);
  return (short)cv.u;
}

// device-scope load (bypass possibly-stale L1 after grid barrier)
__device__ __forceinline__ float ws_ld(const float* p) {
  return __hip_atomic_load(p, __ATOMIC_RELAXED, __HIP_MEMORY_SCOPE_AGENT);
}

// Manual grid barrier: monotone counter, target = k*NBLK for the k-th barrier.
// __syncthreads() drains vmcnt(0) first, so prior global atomics are complete
// before the arrive-increment. (HW-validated rounds 4-13 at NBLK=256.)
__device__ __forceinline__ void gridbar(int* cnt, int tid, int target) {
  __syncthreads();
  if (tid == 0) {
    __hip_atomic_fetch_add(cnt, 1, __ATOMIC_ACQ_REL, __HIP_MEMORY_SCOPE_AGENT);
    while (__hip_atomic_load(cnt, __ATOMIC_ACQUIRE,
                             __HIP_MEMORY_SCOPE_AGENT) < target) {
      __builtin_amdgcn_s_sleep(8);
    }
  }
  __syncthreads();
}

// Build 14-ch geometric feature and h = w1 @ x (16 channels) for one position.
__device__ __forceinline__ void geom_h(
    const float* __restrict__ xyz, const float* __restrict__ dist,
    const float* __restrict__ nrm, const float* __restrict__ ang,
    const float* __restrict__ w1, int b, int rem, float h[HIDn]) {
  const int cbase = rem & ~(Kn - 1);   // k = 0 element of this (b, n)
  float x[14];
  const float invd = 1.0f / (1.0f + dist[b * NK + rem]);
  float xe = 0.f, ne = 0.f;
#pragma unroll
  for (int d = 0; d < 3; ++d) {
    const int base = (b * 3 + d) * NK;
    const float gx = xyz[base + rem];
    const float gn = nrm[base + rem];
    const float cn = nrm[base + cbase];
    const float ga = ang[base + rem];
    const float nd = gn - cn;
    x[d] = gx; x[4 + d] = gn; x[7 + d] = nd; x[11 + d] = ga;
    xe += gx * gx; ne += nd * nd;
  }
  x[3]  = sqrtf(xe);
  x[10] = sqrtf(ne);
#pragma unroll
  for (int i = 0; i < 14; ++i) x[i] *= invd;
#pragma unroll
  for (int o = 0; o < HIDn; ++o) {
    float s = 0.f;
#pragma unroll
    for (int c = 0; c < 14; ++c) s = fmaf(w1[o * 14 + c], x[c], s);
    h[o] = s;
  }
}

__global__ __launch_bounds__(512) void k0_zero(float* __restrict__ ws) {
  if (threadIdx.x < WS_TOT) ws[threadIdx.x] = 0.f;
}

// Persistent kernel = round-10 baseline (83.5 us, best measured) with ONE
// change: A-fragment build uses packed bf16 multiplies (__hmul2 ->
// v_pk_mul_bf16 on gfx950). fA is converted to bf16 once and splat; 4 hmul2
// against the packed score pairs replace ~24 VALU ops (2 unpack + 2 mul +
// 2 cvt per element-pair). k3-lineage profiling showed VALU as the GEMM's
// top pipe; this is the direct cut.
// Lessons pinned: 1024-thr blocks have a 64-VGPR arch budget (r4-11); no
// setprio (r12 regressed); butterfly phase A (r13 transpose-reduce was a
// 32-way bank conflict); separate __shared__ arrays (r9).
__global__ __launch_bounds__(NTHR, 1) void kmain(
    const float* __restrict__ xyz, const float* __restrict__ dist,
    const float* __restrict__ nrm, const float* __restrict__ ang,
    const float* __restrict__ feature, const float* __restrict__ w1,
    const float* __restrict__ g1, const float* __restrict__ b1,
    const float* __restrict__ w2, const float* __restrict__ bias2,
    const float* __restrict__ wb, const float* __restrict__ gamma,
    const float* __restrict__ beta, float* __restrict__ ws,
    float* __restrict__ out) {
  __shared__ short lds_b[64 * 64 * 8];       // 64 KB: frag fi=kk*2+ct, lane, 8
  __shared__ unsigned park[16 * NTHR];       // 64 KB g0 acc park (2xbf16/word)
  __shared__ float red[16][128];             // 8 KB reductions
  __shared__ float bnp[160];  // [0:16] sc1 [16:32] sh1 [32:96] sc2 [96:160] sh2

  int* const bar = (int*)(ws + WS_BAR);

  const int tid = threadIdx.x;
  const int l   = tid & 63;
  const int w   = tid >> 6;          // wave 0..15
  const int lg  = l >> 5;            // lane half 0..1 (k-group for 32x32x16)
  const int col = l & 31;            // A row (position) / B-D col (output)

  const int blk = blockIdx.x;
  const int pos = blk * NTHR + tid;  // this thread's position (phases A & C)
  const int b   = pos >> 16;         // uniform per block (1024 | NK)
  const int rem = pos & (NK - 1);

  // ---- stage Wb into LDS as 32x32x16 B fragments (round-8-validated) ----
#pragma unroll
  for (int ff = 0; ff < 4; ++ff) {
    const int fi = w * 4 + ff;
    const int kk = fi >> 1;
    const int ct = fi & 1;
    const int c  = kk * 2 + lg;
    const int o  = ct * 32 + col;
    bf16x8 frag;
#pragma unroll
    for (int j = 0; j < 8; ++j) frag[j] = f2bf(wb[c * 512 + j * 64 + o]);
    *reinterpret_cast<bf16x8*>(&lds_b[(fi * 64 + l) * 8]) = frag;
  }

  // ---- phase A: geom + h (kept in regs), BN1 sums (r10 butterfly) ----
  float h[HIDn];
  geom_h(xyz, dist, nrm, ang, w1, b, rem, h);
  {
    float v[32];
#pragma unroll
    for (int i = 0; i < 16; ++i) { v[i] = h[i]; v[16 + i] = h[i] * h[i]; }
#pragma unroll
    for (int off = 32; off >= 1; off >>= 1) {
#pragma unroll
      for (int i = 0; i < 32; ++i) v[i] += __shfl_xor(v[i], off);
    }
    float mv = 0.f;
#pragma unroll
    for (int i = 0; i < 32; ++i) { if (l == i) mv = v[i]; }
    if (l < 32) red[w][l] = mv;
    __syncthreads();
    if (tid < 32) {
      float tot = 0.f;
#pragma unroll
      for (int ww = 0; ww < 16; ++ww) tot += red[ww][tid];
      atomicAdd(&ws[WS_SUM1 + tid], tot);   // [0:16]=sum, [16:32]=sumsq
    }
  }

  gridbar(bar, tid, NBLK);   // ---- grid barrier #1 ----

  // ---- phase B: every block finalizes BN1 ----
  if (tid < HIDn) {
    const float inv  = 1.0f / (float)PTOT;
    const float mean = ws_ld(&ws[WS_SUM1 + tid]) * inv;
    const float var  = ws_ld(&ws[WS_SQ1 + tid]) * inv - mean * mean;
    const float s    = g1[tid] * rsqrtf(var + EPSf);
    bnp[tid]      = s;
    bnp[16 + tid] = b1[tid] - mean * s;
  }
  __syncthreads();

  // ---- phase C: scorenet from cached h; pack scores to bf16 words ----
  unsigned scp[4];
  {
#pragma unroll
    for (int o = 0; o < HIDn; ++o)
      h[o] = fmaxf(fmaf(h[o], bnp[o], bnp[16 + o]), 0.f);
    float s[Mn];
#pragma unroll
    for (int m = 0; m < Mn; ++m) {
      float a = bias2[m];
#pragma unroll
      for (int j = 0; j < HIDn; ++j) a = fmaf(w2[m * HIDn + j], h[j], a);
      s[m] = a;
    }
    float mx = s[0];
#pragma unroll
    for (int m = 1; m < Mn; ++m) mx = fmaxf(mx, s[m]);
    float sc[Mn];
    float ssum = 0.f;
#pragma unroll
    for (int m = 0; m < Mn; ++m) { sc[m] = expf(s[m] - mx); ssum += sc[m]; }
    const float inv = 1.0f / (ssum + expf(-mx));   // softmax_one
#pragma unroll
    for (int m = 0; m < Mn; ++m) sc[m] *= inv;
#pragma unroll
    for (int j = 0; j < 4; ++j) {
      scp[j] = (unsigned)(unsigned short)f2bf(sc[2 * j]) |
               ((unsigned)(unsigned short)f2bf(sc[2 * j + 1]) << 16);
    }
  }

  // ---- GEMM: wave owns 64 positions; two sequential groups of 32 ----
  const int wrem = (blk * NTHR + w * 64) & (NK - 1);
  const float* fbase = feature + (size_t)b * CIN * NK + wrem;
  f32x16 acc0, acc1;   // ct=0 / ct=1 col-tiles of the CURRENT group

#pragma unroll
  for (int grp = 0; grp < 2; ++grp) {
    unsigned s0p[4];
#pragma unroll
    for (int j = 0; j < 4; ++j) s0p[j] = __shfl(scp[j], grp * 32 + col);
#pragma unroll
    for (int i = 0; i < 16; ++i) { acc0[i] = 0.f; acc1[i] = 0.f; }

    const float* fp = fbase + (size_t)lg * NK + grp * 32 + col;
#pragma unroll 8
    for (int kk = 0; kk < 32; ++kk) {
      const float fA = *fp;
      fp += 2 * NK;
      // A-build via packed bf16 mul: bf16(fA) splat pair x packed scores.
      const unsigned fab = (unsigned)(unsigned short)f2bf(fA);
      const unsigned fap = fab | (fab << 16);
      union { unsigned u[4]; bf16x8 v8; } A;
#pragma unroll
      for (int j = 0; j < 4; ++j) {
        const __hip_bfloat162 r =
            __hmul2(*reinterpret_cast<const __hip_bfloat162*>(&fap),
                    *reinterpret_cast<const __hip_bfloat162*>(&s0p[j]));
        A.u[j] = *reinterpret_cast<const unsigned*>(&r);
      }
      const bf16x8 a = A.v8;
      const bf16x8 b0 =
          *reinterpret_cast<const bf16x8*>(&lds_b[((kk * 2 + 0) * 64 + l) * 8]);
      const bf16x8 b1 =
          *reinterpret_cast<const bf16x8*>(&lds_b[((kk * 2 + 1) * 64 + l) * 8]);
      acc0 = __builtin_amdgcn_mfma_f32_32x32x16_bf16(a, b0, acc0, 0, 0, 0);
      acc1 = __builtin_amdgcn_mfma_f32_32x32x16_bf16(a, b1, acc1, 0, 0, 0);
    }

    // BN2 partials for this group (deferred out of the K-loop)
    {
      float s0s = 0.f, q0s = 0.f, s1s = 0.f, q1s = 0.f;
#pragma unroll
      for (int i = 0; i < 16; ++i) {
        s0s += acc0[i]; q0s += acc0[i] * acc0[i];
        s1s += acc1[i]; q1s += acc1[i] * acc1[i];
      }
      s0s += __shfl_xor(s0s, 32); q0s += __shfl_xor(q0s, 32);
      s1s += __shfl_xor(s1s, 32); q1s += __shfl_xor(q1s, 32);
      if (l < 32) {
        if (grp == 0) {
          red[w][col]      = s0s; red[w][32 + col] = s1s;
          red[w][64 + col] = q0s; red[w][96 + col] = q1s;
        } else {
          red[w][col]      += s0s; red[w][32 + col] += s1s;
          red[w][64 + col] += q0s; red[w][96 + col] += q1s;
        }
      }
    }

    if (grp == 0) {
      // park g0 acc as packed bf16 pairs: word idx = ct*8+i (conflict-free)
#pragma unroll
      for (int i = 0; i < 8; ++i) {
        const unsigned w0 =
            (unsigned)(unsigned short)f2bf(acc0[2 * i]) |
            ((unsigned)(unsigned short)f2bf(acc0[2 * i + 1]) << 16);
        const unsigned w1 =
            (unsigned)(unsigned short)f2bf(acc1[2 * i]) |
            ((unsigned)(unsigned short)f2bf(acc1[2 * i + 1]) << 16);
        park[i * NTHR + tid]       = w0;
        park[(8 + i) * NTHR + tid] = w1;
      }
    }
  }

  // ---- cross-wave BN2 reduction + atomics ----
  __syncthreads();
  if (tid < 128) {
    float tot = 0.f;
#pragma unroll
    for (int ww = 0; ww < 16; ++ww) tot += red[ww][tid];
    atomicAdd(&ws[WS_SUM2 + tid], tot);   // [64:128]=sum2, [128:192]=sq2
  }

  gridbar(bar, tid, 2 * NBLK);   // ---- grid barrier #2 ----

  // ---- phase D: every block finalizes BN2 ----
  if (tid < COUT) {
    const float inv  = 1.0f / (float)PTOT;
    const float mean = ws_ld(&ws[WS_SUM2 + tid]) * inv;
    const float var  = ws_ld(&ws[WS_SQ2 + tid]) * inv - mean * mean;
    const float s    = gamma[tid] * rsqrtf(var + EPSf);
    bnp[32 + tid] = s;
    bnp[96 + tid] = beta[tid] - mean * s;
  }
  __syncthreads();

  // ---- phase E: BN2 + ReLU; g1 from regs, g0 from park ----
  // D mapping (m74/m101): o = ct*32+col; reg r -> position (r&3)+8*(r>>2)+4*lg
  // -> reg-quad q = 4 consecutive positions at q*8 + 4*lg.
  float* obase = out + (size_t)b * COUT * NK + wrem;
#pragma unroll
  for (int ct = 0; ct < 2; ++ct) {
    const int o = ct * 32 + col;
    const float scl = bnp[32 + o];
    const float sh  = bnp[96 + o];
    float* orow = obase + (size_t)o * NK;
#pragma unroll
    for (int q = 0; q < 4; ++q) {
      // g1 (positions +32..63) from registers, exact
      f32x4 v1;
#pragma unroll
      for (int i = 0; i < 4; ++i) {
        const float vv = ct ? acc1[q * 4 + i] : acc0[q * 4 + i];
        v1[i] = fmaxf(fmaf(vv, scl, sh), 0.f);
      }
      *reinterpret_cast<f32x4*>(&orow[32 + q * 8 + 4 * lg]) = v1;
      // g0 (positions +0..31) from bf16 park
      const unsigned wa = park[(ct * 8 + q * 2 + 0) * NTHR + tid];
      const unsigned wb2 = park[(ct * 8 + q * 2 + 1) * NTHR + tid];
      f32x4 v0;
      v0[0] = __uint_as_float(wa << 16);
      v0[1] = __uint_as_float(wa & 0xffff0000u);
      v0[2] = __uint_as_float(wb2 << 16);
      v0[3] = __uint_as_float(wb2 & 0xffff0000u);
#pragma unroll
      for (int i = 0; i < 4; ++i) v0[i] = fmaxf(fmaf(v0[i], scl, sh), 0.f);
      *reinterpret_cast<f32x4*>(&orow[q * 8 + 4 * lg]) = v0;
    }
  }
}

}  // namespace

extern "C" void kernel_launch(void* const* d_in, const int* in_sizes, int n_in,
                              void* d_out, int out_size, void* d_ws, size_t ws_size,
                              hipStream_t stream) {
  const float* xyz     = (const float*)d_in[0];
  const float* dist    = (const float*)d_in[1];
  const float* nrm     = (const float*)d_in[2];
  const float* ang     = (const float*)d_in[3];
  const float* feature = (const float*)d_in[4];
  const float* w1      = (const float*)d_in[5];
  const float* g1      = (const float*)d_in[6];
  const float* b1      = (const float*)d_in[7];
  const float* w2      = (const float*)d_in[8];
  const float* bias2   = (const float*)d_in[9];
  const float* wb      = (const float*)d_in[10];
  const float* gamma   = (const float*)d_in[11];
  const float* beta    = (const float*)d_in[12];
  float* out = (float*)d_out;
  float* ws  = (float*)d_ws;

  hipLaunchKernelGGL(k0_zero, dim3(1), dim3(512), 0, stream, ws);
  hipLaunchKernelGGL(kmain, dim3(NBLK), dim3(NTHR), 0, stream,
                     xyz, dist, nrm, ang, feature, w1, g1, b1,
                     w2, bias2, wb, gamma, beta, ws, out);
}

// Round 16
// 82.287 us; speedup vs baseline: 4.1519x; 1.1205x over previous
//
#include <hip/hip_runtime.h>
#include <hip/hip_bf16.h>
#include <math.h>

namespace {

constexpr int Kn   = 32;
constexpr int CIN  = 64;
constexpr int COUT = 64;
constexpr int Mn   = 8;
constexpr int HIDn = 16;
constexpr int NK   = 65536;         // N*K
constexpr int PTOT = 262144;        // B*N*K
constexpr float EPSf = 1e-5f;

constexpr int NBLK = 256;           // == #CUs: 1 block/CU, all resident
constexpr int NTHR = 1024;          // 16 waves

// ws float-offset layout
constexpr int WS_SUM1 = 0;    // 16 floats
constexpr int WS_SQ1  = 16;   // 16
constexpr int WS_SUM2 = 64;   // 64
constexpr int WS_SQ2  = 128;  // 64
constexpr int WS_BAR  = 192;  // int barrier counter (monotone)
constexpr int WS_TOT  = 256;

typedef short bf16x8  __attribute__((ext_vector_type(8)));
typedef float f32x4   __attribute__((ext_vector_type(4)));
typedef float f32x16  __attribute__((ext_vector_type(16)));

__device__ __forceinline__ short f2bf(float f) {
  union { __hip_bfloat16 h; unsigned short u; } cv;
  cv.h = __float2bfloat16(f);
  return (short)cv.u;
}

// device-scope load (bypass possibly-stale L1 after grid barrier)
__device__ __forceinline__ float ws_ld(const float* p) {
  return __hip_atomic_load(p, __ATOMIC_RELAXED, __HIP_MEMORY_SCOPE_AGENT);
}

// Manual grid barrier: monotone counter, target = k*NBLK for the k-th barrier.
// __syncthreads() drains vmcnt(0) first, so prior global atomics are complete
// before the arrive-increment. (HW-validated rounds 4-15.)
__device__ __forceinline__ void gridbar(int* cnt, int tid, int target) {
  __syncthreads();
  if (tid == 0) {
    __hip_atomic_fetch_add(cnt, 1, __ATOMIC_ACQ_REL, __HIP_MEMORY_SCOPE_AGENT);
    while (__hip_atomic_load(cnt, __ATOMIC_ACQUIRE,
                             __HIP_MEMORY_SCOPE_AGENT) < target) {
      __builtin_amdgcn_s_sleep(8);
    }
  }
  __syncthreads();
}

// Build 14-ch geometric feature and h = w1 @ x (16 channels) for one position.
__device__ __forceinline__ void geom_h(
    const float* __restrict__ xyz, const float* __restrict__ dist,
    const float* __restrict__ nrm, const float* __restrict__ ang,
    const float* __restrict__ w1, int b, int rem, float h[HIDn]) {
  const int cbase = rem & ~(Kn - 1);   // k = 0 element of this (b, n)
  float x[14];
  const float invd = 1.0f / (1.0f + dist[b * NK + rem]);
  float xe = 0.f, ne = 0.f;
#pragma unroll
  for (int d = 0; d < 3; ++d) {
    const int base = (b * 3 + d) * NK;
    const float gx = xyz[base + rem];
    const float gn = nrm[base + rem];
    const float cn = nrm[base + cbase];
    const float ga = ang[base + rem];
    const float nd = gn - cn;
    x[d] = gx; x[4 + d] = gn; x[7 + d] = nd; x[11 + d] = ga;
    xe += gx * gx; ne += nd * nd;
  }
  x[3]  = sqrtf(xe);
  x[10] = sqrtf(ne);
#pragma unroll
  for (int i = 0; i < 14; ++i) x[i] *= invd;
#pragma unroll
  for (int o = 0; o < HIDn; ++o) {
    float s = 0.f;
#pragma unroll
    for (int c = 0; c < 14; ++c) s = fmaf(w1[o * 14 + c], x[c], s);
    h[o] = s;
  }
}

__global__ __launch_bounds__(512) void k0_zero(float* __restrict__ ws) {
  if (threadIdx.x < WS_TOT) ws[threadIdx.x] = 0.f;
}

// Persistent kernel — EXACT round-10 configuration (best measured: 83.5 us,
// absmax 0.03125). 32x32x16 MFMA, packed bf16 scores (f32-path A-build), BN2
// partials deferred out of the K-loop, g0 acc parked in LDS as bf16, unroll 8.
// Pinned lessons (all HW-measured on this problem):
//  - 1024-thr blocks have a fixed 64-VGPR arch budget; design to it (r4-r11).
//  - No setprio in the lockstep K-loop (r12: -7%).
//  - Butterfly phase-A reduce; LDS transpose-reduce = 32-way conflict (r13).
//  - Distinct __shared__ arrays; merging kills alias analysis (r9).
//  - A-build via f32 mul + cvt; packed __hmul2 perturbs schedule (r15: -10%).
//  - K-loop is not load-latency-bound (r10 unroll null); VALU not critical
//    (r15 cut VALU, dur worse). Residual stall is structural.
__global__ __launch_bounds__(NTHR, 1) void kmain(
    const float* __restrict__ xyz, const float* __restrict__ dist,
    const float* __restrict__ nrm, const float* __restrict__ ang,
    const float* __restrict__ feature, const float* __restrict__ w1,
    const float* __restrict__ g1, const float* __restrict__ b1,
    const float* __restrict__ w2, const float* __restrict__ bias2,
    const float* __restrict__ wb, const float* __restrict__ gamma,
    const float* __restrict__ beta, float* __restrict__ ws,
    float* __restrict__ out) {
  __shared__ short lds_b[64 * 64 * 8];       // 64 KB: frag fi=kk*2+ct, lane, 8
  __shared__ unsigned park[16 * NTHR];       // 64 KB g0 acc park (2xbf16/word)
  __shared__ float red[16][128];             // 8 KB reductions
  __shared__ float bnp[160];  // [0:16] sc1 [16:32] sh1 [32:96] sc2 [96:160] sh2

  int* const bar = (int*)(ws + WS_BAR);

  const int tid = threadIdx.x;
  const int l   = tid & 63;
  const int w   = tid >> 6;          // wave 0..15
  const int lg  = l >> 5;            // lane half 0..1 (k-group for 32x32x16)
  const int col = l & 31;            // A row (position) / B-D col (output)

  const int blk = blockIdx.x;
  const int pos = blk * NTHR + tid;  // this thread's position (phases A & C)
  const int b   = pos >> 16;         // uniform per block (1024 | NK)
  const int rem = pos & (NK - 1);

  // ---- stage Wb into LDS as 32x32x16 B fragments (round-8-validated) ----
  // frag fi = kk*2+ct; lane l elem j = Wb[c = kk*2+lg][m = j][o = ct*32+col]
#pragma unroll
  for (int ff = 0; ff < 4; ++ff) {
    const int fi = w * 4 + ff;
    const int kk = fi >> 1;
    const int ct = fi & 1;
    const int c  = kk * 2 + lg;
    const int o  = ct * 32 + col;
    bf16x8 frag;
#pragma unroll
    for (int j = 0; j < 8; ++j) frag[j] = f2bf(wb[c * 512 + j * 64 + o]);
    *reinterpret_cast<bf16x8*>(&lds_b[(fi * 64 + l) * 8]) = frag;
  }

  // ---- phase A: geom + h (kept in regs), BN1 sums ----
  float h[HIDn];
  geom_h(xyz, dist, nrm, ang, w1, b, rem, h);
  {
    float v[32];
#pragma unroll
    for (int i = 0; i < 16; ++i) { v[i] = h[i]; v[16 + i] = h[i] * h[i]; }
#pragma unroll
    for (int off = 32; off >= 1; off >>= 1) {
#pragma unroll
      for (int i = 0; i < 32; ++i) v[i] += __shfl_xor(v[i], off);
    }
    float mv = 0.f;
#pragma unroll
    for (int i = 0; i < 32; ++i) { if (l == i) mv = v[i]; }
    if (l < 32) red[w][l] = mv;
    __syncthreads();
    if (tid < 32) {
      float tot = 0.f;
#pragma unroll
      for (int ww = 0; ww < 16; ++ww) tot += red[ww][tid];
      atomicAdd(&ws[WS_SUM1 + tid], tot);   // [0:16]=sum, [16:32]=sumsq
    }
  }

  gridbar(bar, tid, NBLK);   // ---- grid barrier #1 ----

  // ---- phase B: every block finalizes BN1 ----
  if (tid < HIDn) {
    const float inv  = 1.0f / (float)PTOT;
    const float mean = ws_ld(&ws[WS_SUM1 + tid]) * inv;
    const float var  = ws_ld(&ws[WS_SQ1 + tid]) * inv - mean * mean;
    const float s    = g1[tid] * rsqrtf(var + EPSf);
    bnp[tid]      = s;
    bnp[16 + tid] = b1[tid] - mean * s;
  }
  __syncthreads();

  // ---- phase C: scorenet from cached h; pack scores to bf16 words ----
  unsigned scp[4];
  {
#pragma unroll
    for (int o = 0; o < HIDn; ++o)
      h[o] = fmaxf(fmaf(h[o], bnp[o], bnp[16 + o]), 0.f);
    float s[Mn];
#pragma unroll
    for (int m = 0; m < Mn; ++m) {
      float a = bias2[m];
#pragma unroll
      for (int j = 0; j < HIDn; ++j) a = fmaf(w2[m * HIDn + j], h[j], a);
      s[m] = a;
    }
    float mx = s[0];
#pragma unroll
    for (int m = 1; m < Mn; ++m) mx = fmaxf(mx, s[m]);
    float sc[Mn];
    float ssum = 0.f;
#pragma unroll
    for (int m = 0; m < Mn; ++m) { sc[m] = expf(s[m] - mx); ssum += sc[m]; }
    const float inv = 1.0f / (ssum + expf(-mx));   // softmax_one
#pragma unroll
    for (int m = 0; m < Mn; ++m) sc[m] *= inv;
#pragma unroll
    for (int j = 0; j < 4; ++j) {
      scp[j] = (unsigned)(unsigned short)f2bf(sc[2 * j]) |
               ((unsigned)(unsigned short)f2bf(sc[2 * j + 1]) << 16);
    }
  }

  // ---- GEMM: wave owns 64 positions; two sequential groups of 32 ----
  const int wrem = (blk * NTHR + w * 64) & (NK - 1);
  const float* fbase = feature + (size_t)b * CIN * NK + wrem;
  f32x16 acc0, acc1;   // ct=0 / ct=1 col-tiles of the CURRENT group

#pragma unroll
  for (int grp = 0; grp < 2; ++grp) {
    unsigned s0p[4];
#pragma unroll
    for (int j = 0; j < 4; ++j) s0p[j] = __shfl(scp[j], grp * 32 + col);
#pragma unroll
    for (int i = 0; i < 16; ++i) { acc0[i] = 0.f; acc1[i] = 0.f; }

    const float* fp = fbase + (size_t)lg * NK + grp * 32 + col;
#pragma unroll 8
    for (int kk = 0; kk < 32; ++kk) {
      const float fA = *fp;
      fp += 2 * NK;
      bf16x8 a;
#pragma unroll
      for (int j = 0; j < 4; ++j) {
        const float slo = __uint_as_float(s0p[j] << 16);
        const float shi = __uint_as_float(s0p[j] & 0xffff0000u);
        a[2 * j]     = f2bf(fA * slo);
        a[2 * j + 1] = f2bf(fA * shi);
      }
      const bf16x8 b0 =
          *reinterpret_cast<const bf16x8*>(&lds_b[((kk * 2 + 0) * 64 + l) * 8]);
      const bf16x8 b1 =
          *reinterpret_cast<const bf16x8*>(&lds_b[((kk * 2 + 1) * 64 + l) * 8]);
      acc0 = __builtin_amdgcn_mfma_f32_32x32x16_bf16(a, b0, acc0, 0, 0, 0);
      acc1 = __builtin_amdgcn_mfma_f32_32x32x16_bf16(a, b1, acc1, 0, 0, 0);
    }

    // BN2 partials for this group (deferred out of the K-loop)
    {
      float s0s = 0.f, q0s = 0.f, s1s = 0.f, q1s = 0.f;
#pragma unroll
      for (int i = 0; i < 16; ++i) {
        s0s += acc0[i]; q0s += acc0[i] * acc0[i];
        s1s += acc1[i]; q1s += acc1[i] * acc1[i];
      }
      s0s += __shfl_xor(s0s, 32); q0s += __shfl_xor(q0s, 32);
      s1s += __shfl_xor(s1s, 32); q1s += __shfl_xor(q1s, 32);
      if (l < 32) {
        if (grp == 0) {
          red[w][col]      = s0s; red[w][32 + col] = s1s;
          red[w][64 + col] = q0s; red[w][96 + col] = q1s;
        } else {
          red[w][col]      += s0s; red[w][32 + col] += s1s;
          red[w][64 + col] += q0s; red[w][96 + col] += q1s;
        }
      }
    }

    if (grp == 0) {
      // park g0 acc as packed bf16 pairs: word idx = ct*8+i (conflict-free)
#pragma unroll
      for (int i = 0; i < 8; ++i) {
        const unsigned w0 =
            (unsigned)(unsigned short)f2bf(acc0[2 * i]) |
            ((unsigned)(unsigned short)f2bf(acc0[2 * i + 1]) << 16);
        const unsigned w1 =
            (unsigned)(unsigned short)f2bf(acc1[2 * i]) |
            ((unsigned)(unsigned short)f2bf(acc1[2 * i + 1]) << 16);
        park[i * NTHR + tid]       = w0;
        park[(8 + i) * NTHR + tid] = w1;
      }
    }
  }

  // ---- cross-wave BN2 reduction + atomics ----
  __syncthreads();
  if (tid < 128) {
    float tot = 0.f;
#pragma unroll
    for (int ww = 0; ww < 16; ++ww) tot += red[ww][tid];
    atomicAdd(&ws[WS_SUM2 + tid], tot);   // [64:128]=sum2, [128:192]=sq2
  }

  gridbar(bar, tid, 2 * NBLK);   // ---- grid barrier #2 ----

  // ---- phase D: every block finalizes BN2 ----
  if (tid < COUT) {
    const float inv  = 1.0f / (float)PTOT;
    const float mean = ws_ld(&ws[WS_SUM2 + tid]) * inv;
    const float var  = ws_ld(&ws[WS_SQ2 + tid]) * inv - mean * mean;
    const float s    = gamma[tid] * rsqrtf(var + EPSf);
    bnp[32 + tid] = s;
    bnp[96 + tid] = beta[tid] - mean * s;
  }
  __syncthreads();

  // ---- phase E: BN2 + ReLU; g1 from regs, g0 from park ----
  // D mapping (m74/m101): o = ct*32+col; reg r -> position (r&3)+8*(r>>2)+4*lg
  // -> reg-quad q = 4 consecutive positions at q*8 + 4*lg.
  float* obase = out + (size_t)b * COUT * NK + wrem;
#pragma unroll
  for (int ct = 0; ct < 2; ++ct) {
    const int o = ct * 32 + col;
    const float scl = bnp[32 + o];
    const float sh  = bnp[96 + o];
    float* orow = obase + (size_t)o * NK;
#pragma unroll
    for (int q = 0; q < 4; ++q) {
      // g1 (positions +32..63) from registers, exact
      f32x4 v1;
#pragma unroll
      for (int i = 0; i < 4; ++i) {
        const float vv = ct ? acc1[q * 4 + i] : acc0[q * 4 + i];
        v1[i] = fmaxf(fmaf(vv, scl, sh), 0.f);
      }
      *reinterpret_cast<f32x4*>(&orow[32 + q * 8 + 4 * lg]) = v1;
      // g0 (positions +0..31) from bf16 park
      const unsigned wa = park[(ct * 8 + q * 2 + 0) * NTHR + tid];
      const unsigned wb2 = park[(ct * 8 + q * 2 + 1) * NTHR + tid];
      f32x4 v0;
      v0[0] = __uint_as_float(wa << 16);
      v0[1] = __uint_as_float(wa & 0xffff0000u);
      v0[2] = __uint_as_float(wb2 << 16);
      v0[3] = __uint_as_float(wb2 & 0xffff0000u);
#pragma unroll
      for (int i = 0; i < 4; ++i) v0[i] = fmaxf(fmaf(v0[i], scl, sh), 0.f);
      *reinterpret_cast<f32x4*>(&orow[q * 8 + 4 * lg]) = v0;
    }
  }
}

}  // namespace

extern "C" void kernel_launch(void* const* d_in, const int* in_sizes, int n_in,
                              void* d_out, int out_size, void* d_ws, size_t ws_size,
                              hipStream_t stream) {
  const float* xyz     = (const float*)d_in[0];
  const float* dist    = (const float*)d_in[1];
  const float* nrm     = (const float*)d_in[2];
  const float* ang     = (const float*)d_in[3];
  const float* feature = (const float*)d_in[4];
  const float* w1      = (const float*)d_in[5];
  const float* g1      = (const float*)d_in[6];
  const float* b1      = (const float*)d_in[7];
  const float* w2      = (const float*)d_in[8];
  const float* bias2   = (const float*)d_in[9];
  const float* wb      = (const float*)d_in[10];
  const float* gamma   = (const float*)d_in[11];
  const float* beta    = (const float*)d_in[12];
  float* out = (float*)d_out;
  float* ws  = (float*)d_ws;

  hipLaunchKernelGGL(k0_zero, dim3(1), dim3(512), 0, stream, ws);
  hipLaunchKernelGGL(kmain, dim3(NBLK), dim3(NTHR), 0, stream,
                     xyz, dist, nrm, ang, feature, w1, g1, b1,
                     w2, bias2, wb, gamma, beta, ws, out);
}